// Round 2
// 1090.261 us; speedup vs baseline: 2.8775x; 2.8775x over previous
//
#include <hip/hip_runtime.h>

// FlexibleScanpathHistoryEncoding
// out[b,o,p] = sum_{c,kh,kw} xmask[b,c,p+kh,p+kw] * W[c&3, o, c>>2, kh, kw] + sum_f valid[b,f]*bias[f,o]
//
// Round 1 (resubmit after infra timeout): f16 MFMA implicit-GEMM (fp32 accumulate).
//   prep_w_k: fp32 weights -> f16, layout [phase=(kw,chalf)][kh][oc][c32] (linear)
//   prep_x_k: fp32 NCHW x -> f16 NHWC with nan_to_num + fixation mask folded in,
//             LDS XOR-swizzle pre-baked into the global layout (m173 pattern)
//   fse_main: 128oc x (16x32 px) per block, 8 waves, mfma_f32_32x32x16_f16,
//             x-tile resident in LDS for all 9 taps, per-(kw,chalf) weight phases
//             with register prefetch (T14). Stores coalesced along ow.

#define B_    32
#define CIN   64
#define HH    192
#define WW    192
#define OUTC  128
#define HO    190
#define WO    190

// ---- old fp32 fallback tile params ----
#define OC_T  64
#define OH_T  4
#define OW_T  32
#define CC    16

// ---- new MFMA tile params ----
#define TOW   32                  // output cols per block
#define TOH   16                  // output rows per block
#define XROWS 18                  // TOH + 2
#define XCOLS 34                  // TOW + 2
#define XROWB (XCOLS*CIN*2)       // 4352 bytes per x-tile row
#define XBYTES (XROWS*XROWB)      // 78336 bytes
#define WPHASE (3*OUTC*32*2)      // 24576 bytes per (kw, c-half) phase
#define XF_OFF (2u<<20)           // xf offset in workspace

typedef _Float16 f16;
typedef __attribute__((ext_vector_type(8)))  _Float16 f16x8;
typedef __attribute__((ext_vector_type(16))) float    f32x16;
typedef __attribute__((ext_vector_type(4)))  float    float4v;

// ============================ prep kernels ============================

// wf[p][kh][oc][c32] linear, p = kw*2 + half, c = half*32 + c32
__global__ __launch_bounds__(256) void prep_w_k(const float* __restrict__ w,
                                                f16* __restrict__ wf)
{
    int idx = blockIdx.x * 256 + threadIdx.x;       // 0..73727
    if (idx >= 6 * 12288) return;
    int p   = idx / 12288;
    int r   = idx - p * 12288;
    int kh  = r >> 12;
    int r2  = r & 4095;
    int oc  = r2 >> 5;
    int c32 = r2 & 31;
    int kw  = p >> 1, half = p & 1;
    int c = half * 32 + c32;
    int f = c & 3, j = c >> 2;
    float v = w[(((size_t)(f * OUTC + oc) * 16 + j) * 3 + kh) * 3 + kw];
    wf[idx] = (f16)v;
}

// xf[b][h][w][c-swizzled]: phys half idx = ((c>>3) ^ (w&7))*8 + (c&7)
__global__ __launch_bounds__(256) void prep_x_k(const float* __restrict__ x,
                                                f16* __restrict__ xf)
{
    __shared__ __align__(16) f16 tile[64 * 64];
    const int w0 = blockIdx.x * 64;
    const int h  = blockIdx.y;
    const int b  = blockIdx.z;
    const int t  = threadIdx.x;

    float vm[4];
#pragma unroll
    for (int f = 0; f < 4; ++f) {
        float m = x[(size_t)(b * CIN + f) * (HH * WW)];
        vm[f] = (m == m) ? 1.0f : 0.0f;             // fixation valid mask
    }

    const int c = t >> 2;                            // 0..63
    const int q = t & 3;
    const float vmc = vm[c & 3];
    const size_t rowbase = ((size_t)(b * CIN + c) * HH + h) * WW + w0;
#pragma unroll
    for (int i = 0; i < 4; ++i) {
        int wl = q * 4 + i * 16;                     // 0..63
        float4v v = *(const float4v*)&x[rowbase + wl];
#pragma unroll
        for (int e = 0; e < 4; ++e) {
            float val = v[e];
            val = (val == val) ? val : 0.0f;         // nan_to_num
            val *= vmc;                              // fixation mask
            int wle = wl + e;
            tile[wle * 64 + (((c >> 3) ^ (wle & 7)) << 3) + (c & 7)] = (f16)val;
        }
    }
    __syncthreads();
    const size_t obase = ((size_t)(b * HH + h) * WW + w0) * CIN;
    f16x8 a0 = *(const f16x8*)&tile[t * 16];
    f16x8 a1 = *(const f16x8*)&tile[t * 16 + 8];
    *(f16x8*)&xf[obase + t * 16]     = a0;
    *(f16x8*)&xf[obase + t * 16 + 8] = a1;
}

// ============================ main kernel ============================

__global__ __launch_bounds__(512, 2) void fse_main(
    const float* __restrict__ x,        // original fp32 (marker channels)
    const f16*  __restrict__ xf,        // prepped NHWC f16 (masked, swizzled)
    const f16*  __restrict__ wf,        // prepped weights f16
    const float* __restrict__ bias,     // [4][128]
    float* __restrict__ out)            // [32,128,190,190]
{
    __shared__ __align__(16) f16 xlds[XBYTES / 2];   // 78336 B
    __shared__ __align__(16) f16 wlds[WPHASE / 2];   // 24576 B
    __shared__ float bsl[OUTC];                      // masked bias

    const int tw = blockIdx.x, th = blockIdx.y, b = blockIdx.z;
    const int ow0 = tw * TOW, oh0 = th * TOH;
    const int t   = (int)threadIdx.x;
    const int l   = t & 63;
    const int wid = t >> 6;            // wave 0..7
    const int hi  = l >> 5;            // k-group within wave
    const int ln  = l & 31;
    const int r0  = (wid >> 1) * 4;    // wave's output-row base (0,4,8,12)
    const int oc0 = (wid & 1) * 64;    // wave's oc base

    // masked bias
    if (t < OUTC) {
        float s = 0.f;
#pragma unroll
        for (int f = 0; f < 4; ++f) {
            float m = x[(size_t)(b * CIN + f) * (HH * WW)];
            if (m == m) s += bias[f * OUTC + t];
        }
        bsl[t] = s;
    }

    // ---- stage x tile: pure linear 16B copies (swizzle pre-baked in xf) ----
    {
        const size_t xgb = (size_t)b * HH * WW * CIN;
        for (int i = t; i < XBYTES / 16; i += 512) {     // 4896 chunks
            int rr  = i / (XROWB / 16);                  // /272 -> row 0..17
            int q   = i - rr * (XROWB / 16);
            int col = q >> 3;                            // 0..33
            int qq  = q & 7;
            int gh = oh0 + rr; gh = gh > HH - 1 ? HH - 1 : gh;   // clamp: feeds only
            int gw = ow0 + col; gw = gw > WW - 1 ? WW - 1 : gw;  // never-stored outputs
            f16x8 v = *(const f16x8*)&xf[xgb + ((size_t)gh * WW + gw) * CIN + qq * 8];
            *(f16x8*)((char*)xlds + (size_t)rr * XROWB + q * 16) = v;
        }
    }

    // ---- prefetch phase-0 weights into regs ----
    f16x8 wreg[3];
#pragma unroll
    for (int i = 0; i < 3; ++i)
        wreg[i] = *(const f16x8*)&wf[(size_t)(t + i * 512) * 8];

    f32x16 acc[2][4];
#pragma unroll
    for (int m = 0; m < 2; ++m)
#pragma unroll
        for (int n = 0; n < 4; ++n)
#pragma unroll
            for (int e = 0; e < 16; ++e) acc[m][n][e] = 0.f;

    // ---- 6 phases: (kw, c-half) ----
    for (int p = 0; p < 6; ++p) {
        __syncthreads();                     // everyone done reading wlds (prev phase)
        // write staged regs -> wlds, oc-pair-interleaved + XOR swizzled rows
#pragma unroll
        for (int i = 0; i < 3; ++i) {
            int ci  = t + i * 512;           // chunk 0..1535
            int s   = ci & 3;
            int row = ci >> 2;               // kh*128 + oc
            int kh  = row >> 7;
            int oc  = row & 127;
            int ps  = (((oc & 1) << 2) | s) ^ ((oc >> 1) & 7);
            *(f16x8*)((char*)wlds + kh * 8192 + (oc >> 1) * 128 + ps * 16) = wreg[i];
        }
        __syncthreads();                     // wlds visible
        if (p < 5) {                         // T14: issue next-phase loads, hide under MFMA
            const f16* src = wf + (size_t)(p + 1) * 12288;
#pragma unroll
            for (int i = 0; i < 3; ++i)
                wreg[i] = *(const f16x8*)&src[(size_t)(t + i * 512) * 8];
        }

        const int kw   = p >> 1, half = p & 1;
        const int col  = ln + kw;
        const int cx   = col & 7;
        const char* xbase = (const char*)xlds + (size_t)r0 * XROWB + col * 128;
        const int ocA  = oc0 + ln;

#pragma unroll
        for (int ks = 0; ks < 2; ++ks) {
            const int s    = half * 4 + ks * 2 + hi;       // x slot 0..7
            const int xoff = ((s ^ cx) << 4);
            f16x8 xb[6];                                    // 6 rows serve all 3 kh
#pragma unroll
            for (int rr = 0; rr < 6; ++rr)
                xb[rr] = *(const f16x8*)(xbase + rr * XROWB + xoff);
            const int s2 = ks * 2 + hi;                     // 0..3
#pragma unroll
            for (int kh = 0; kh < 3; ++kh) {
                f16x8 wa[2];
#pragma unroll
                for (int m = 0; m < 2; ++m) {
                    int oc = ocA + m * 32;
                    int ps = (((oc & 1) << 2) | s2) ^ ((oc >> 1) & 7);
                    wa[m] = *(const f16x8*)((const char*)wlds + kh * 8192 + (oc >> 1) * 128 + ps * 16);
                }
#pragma unroll
                for (int m = 0; m < 2; ++m)
#pragma unroll
                    for (int n = 0; n < 4; ++n)
                        acc[m][n] = __builtin_amdgcn_mfma_f32_32x32x16_f16(
                            wa[m], xb[n + kh], acc[m][n], 0, 0, 0);
            }
        }
    }

    // ---- epilogue: D col = lane&31 = ow, D row = (reg&3)+8*(reg>>2)+4*hi = oc ----
    const int ow = ow0 + ln;
    if (ow < WO) {
#pragma unroll
        for (int m = 0; m < 2; ++m) {
#pragma unroll
            for (int rI = 0; rI < 16; ++rI) {
                int ocr = oc0 + m * 32 + (rI & 3) + ((rI >> 2) << 3) + (hi << 2);
                float bv = bsl[ocr];
                float* obase = out + (((size_t)b * OUTC + ocr) * HO) * (size_t)WO + ow;
#pragma unroll
                for (int n = 0; n < 4; ++n) {
                    int oh = oh0 + r0 + n;
                    if (oh < HO)
                        obase[(size_t)oh * WO] = acc[m][n][rI] + bv;
                }
            }
        }
    }
}

// ============================ fp32 fallback (previous kernel) ============================

__global__ __launch_bounds__(256) void fse_conv_fp32(
    const float* __restrict__ x,
    const float* __restrict__ w,
    const float* __restrict__ bias,
    float* __restrict__ out)
{
    __shared__ float xs[CC][6][36];
    __shared__ float wsm[CC][9][64];

    const int tw  = blockIdx.x;
    const int th  = blockIdx.y;
    const int bz  = blockIdx.z;
    const int b   = bz >> 1;
    const int ocb = (bz & 1) * OC_T;
    const int ow0 = tw * OW_T;
    const int oh0 = th * OH_T;
    const int t    = (int)threadIdx.x;
    const int lane = t & 31;
    const int og   = t >> 5;

    const size_t xbase = (size_t)b * CIN * HH * WW;

    float vmask[4];
#pragma unroll
    for (int f = 0; f < 4; ++f) {
        float m = x[xbase + (size_t)f * (HH * WW)];
        vmask[f] = (m == m) ? 1.0f : 0.0f;
    }

    float acc[4][8];
#pragma unroll
    for (int r = 0; r < 4; ++r)
#pragma unroll
        for (int i = 0; i < 8; ++i) acc[r][i] = 0.0f;

    for (int c0 = 0; c0 < CIN; c0 += CC) {
        for (int idx = t; idx < CC * 6 * 36; idx += 256) {
            int c   = idx / (6 * 36);
            int rem = idx - c * (6 * 36);
            int r   = rem / 36;
            int col = rem - r * 36;
            float v = 0.0f;
            int gh = oh0 + r;
            int gw = ow0 + col;
            if (col < 34 && gh < HH && gw < WW) {
                v = x[xbase + (size_t)(c0 + c) * (HH * WW) + gh * WW + gw];
                v = (v == v) ? v : 0.0f;
                v *= vmask[(c0 + c) & 3];
            }
            xs[c][r][col] = v;
        }
        for (int idx = t; idx < CC * 9 * 64; idx += 256) {
            int cl  = idx / 576;
            int rem = idx - cl * 576;
            int oc  = rem / 9;
            int k   = rem - oc * 9;
            int cg  = c0 + cl;
            int f = cg & 3;
            int j = cg >> 2;
            wsm[cl][k][oc] = w[(((size_t)(f * OUTC + ocb + oc)) * 16 + j) * 9 + k];
        }
        __syncthreads();

        for (int c = 0; c < CC; ++c) {
            float xv[6][3];
#pragma unroll
            for (int rr = 0; rr < 6; ++rr)
#pragma unroll
                for (int kw = 0; kw < 3; ++kw)
                    xv[rr][kw] = xs[c][rr][lane + kw];
#pragma unroll
            for (int kh = 0; kh < 3; ++kh) {
#pragma unroll
                for (int kw = 0; kw < 3; ++kw) {
                    const float4* wp = (const float4*)&wsm[c][kh * 3 + kw][og * 8];
                    float4 wa = wp[0];
                    float4 wb = wp[1];
                    float wv[8] = {wa.x, wa.y, wa.z, wa.w, wb.x, wb.y, wb.z, wb.w};
#pragma unroll
                    for (int r = 0; r < 4; ++r) {
                        float xvv = xv[r + kh][kw];
#pragma unroll
                        for (int i = 0; i < 8; ++i)
                            acc[r][i] = fmaf(xvv, wv[i], acc[r][i]);
                    }
                }
            }
        }
        __syncthreads();
    }

    float bs[8];
#pragma unroll
    for (int i = 0; i < 8; ++i) {
        int oc = ocb + og * 8 + i;
        float s = 0.0f;
#pragma unroll
        for (int f = 0; f < 4; ++f) s += vmask[f] * bias[f * OUTC + oc];
        bs[i] = s;
    }

    const int ow = ow0 + lane;
    if (ow < WO) {
#pragma unroll
        for (int r = 0; r < 4; ++r) {
            int oh = oh0 + r;
            if (oh < HO) {
#pragma unroll
                for (int i = 0; i < 8; ++i) {
                    int oc = ocb + og * 8 + i;
                    out[((size_t)b * OUTC + oc) * (HO * WO) + oh * WO + ow] = acc[r][i] + bs[i];
                }
            }
        }
    }
}

// ============================ launch ============================

extern "C" void kernel_launch(void* const* d_in, const int* in_sizes, int n_in,
                              void* d_out, int out_size, void* d_ws, size_t ws_size,
                              hipStream_t stream)
{
    const float* x    = (const float*)d_in[0];   // [32, 64, 192, 192]
    const float* w    = (const float*)d_in[1];   // [4, 128, 16, 3, 3]
    const float* bias = (const float*)d_in[2];   // [4, 128]
    float* out = (float*)d_out;                  // [32, 128, 190, 190]

    const size_t need = (size_t)XF_OFF + (size_t)B_ * HH * WW * CIN * sizeof(f16); // ~153 MB
    if (d_ws == nullptr || ws_size < need) {
        dim3 grid(6, 48, 64);
        fse_conv_fp32<<<grid, 256, 0, stream>>>(x, w, bias, out);
        return;
    }

    f16* wf = (f16*)d_ws;
    f16* xf = (f16*)((char*)d_ws + XF_OFF);

    prep_w_k<<<dim3(288), dim3(256), 0, stream>>>(w, wf);
    prep_x_k<<<dim3(3, HH, B_), dim3(256), 0, stream>>>(x, xf);
    fse_main<<<dim3(6, 12, B_), dim3(512), 0, stream>>>(x, xf, wf, bias, out);
}